// Round 1
// 1685.839 us; speedup vs baseline: 2.6684x; 2.6684x over previous
//
#include <hip/hip_runtime.h>

#define NTOK 131072
#define DIM 512
#define MSLOT 25
#define TB 16
#define ALPHA 0.2f
#define MOMENTUM 0.8f

typedef unsigned int u32;
typedef unsigned short u16;
typedef _Float16 half8 __attribute__((ext_vector_type(8)));
typedef float floatx16 __attribute__((ext_vector_type(16)));

// order-preserving float<->uint for atomicMax on signed floats
__device__ __forceinline__ u32 f2sort(float f) {
    u32 u = __float_as_uint(f);
    return (u & 0x80000000u) ? ~u : (u | 0x80000000u);
}
__device__ __forceinline__ float sort2f(u32 u) {
    return __uint_as_float((u & 0x80000000u) ? (u ^ 0x80000000u) : ~u);
}

__device__ __forceinline__ u16 f2h_bits(float f) {
    _Float16 h = (_Float16)f;
    u16 u;
    __builtin_memcpy(&u, &h, 2);
    return u;
}

__device__ __forceinline__ void gload16(const void* g, void* l) {
    __builtin_amdgcn_global_load_lds((const __attribute__((address_space(1))) u32*)g,
                                     (__attribute__((address_space(3))) u32*)l, 16, 0, 0);
}

// ---------------- G = cache @ W2^T   (G[j][o] = sum_k cache[j,k] * W[o,512+k]) ----------------
__global__ __launch_bounds__(256) void k_G(const float* __restrict__ W,
                                           const float* __restrict__ C,
                                           float* __restrict__ G) {
    int gid = blockIdx.x * 256 + threadIdx.x;
    if (gid >= MSLOT * DIM) return;
    int j = gid >> 9, o = gid & (DIM - 1);
    const float4* c4 = (const float4*)(C + j * DIM);
    const float4* w4 = (const float4*)(W + (size_t)o * (2 * DIM) + DIM);
    float acc = 0.f;
    for (int kc = 0; kc < DIM / 4; kc++) {
        float4 cv = c4[kc], wv = w4[kc];
        acc += cv.x * wv.x + cv.y * wv.y + cv.z * wv.z + cv.w * wv.w;
    }
    G[j * DIM + o] = acc;
}

// ---------------- pack kernel: build fp16 pre-swizzled B (=[W1^T;G^T-ish]) and cacheT ----------------
// Bhs: 17 K-tiles of 32 KiB. Tile t, byte q in tile: col=q>>6, kg_phys=(q>>4)&3, elem e=(q&15)>>1.
//   logical kg = kg_phys ^ ((col>>1)&3);  k = t*32 + kg*8 + e
//   value    = k<512 ? W[col][k] : (k<537 ? G[k-512][col] : 0)
// Chs: row j (0..31), byte o: gp=(o>>4)&63, e=(o&15)>>1; gl = (gp&~7)|((gp&7)^(j&7)); k=gl*8+e
//   value    = j<25 ? cache[j][k] : 0
#define BHS_U32 139264
#define CHS_U32 8192
__global__ __launch_bounds__(256) void k_pack(const float* __restrict__ W,
                                              const float* __restrict__ C,
                                              const float* __restrict__ G,
                                              u32* __restrict__ Bhs,
                                              u32* __restrict__ Chs) {
    int idx = blockIdx.x * 256 + threadIdx.x;
    if (idx < BHS_U32) {
        int o = idx << 2;
        int t = o >> 15;
        int q = o & 32767;
        int col = q >> 6;
        int kgp = (q >> 4) & 3;
        int e0 = (q & 15) >> 1;
        int s = (col >> 1) & 3;
        int k = t * 32 + ((kgp ^ s) << 3) + e0;
        float f0, f1;
        if (k < DIM) {
            f0 = W[(size_t)col * (2 * DIM) + k];
            f1 = W[(size_t)col * (2 * DIM) + k + 1];
        } else if (k < DIM + MSLOT) {
            int j = k - DIM;
            f0 = G[j * DIM + col];
            f1 = (j + 1 < MSLOT) ? G[(j + 1) * DIM + col] : 0.f;
        } else { f0 = 0.f; f1 = 0.f; }
        Bhs[idx] = (u32)f2h_bits(f0) | ((u32)f2h_bits(f1) << 16);
    } else if (idx < BHS_U32 + CHS_U32) {
        int i2 = idx - BHS_U32;
        int o = i2 << 2;
        int j = o >> 10;
        int gp = (o >> 4) & 63;
        int e0 = (o & 15) >> 1;
        int gl = (gp & ~7) | ((gp & 7) ^ (j & 7));
        int k = (gl << 3) + e0;
        float f0 = (j < MSLOT) ? C[j * DIM + k] : 0.f;
        float f1 = (j < MSLOT) ? C[j * DIM + k + 1] : 0.f;
        Chs[i2] = (u32)f2h_bits(f0) | ((u32)f2h_bits(f1) << 16);
    }
}

// ---------------- text path as one fused MFMA GEMM ----------------
// per block: 64 tokens x 512 outputs; K = 544 = [T(512) | P(25, pad 32)]
// phase 0: T tile -> fp16 swizzled A_lds + row norms (async: Chs->Bsh[1], Btile0->Bsh[0])
// phase 1: scores = A @ cacheT (MFMA) -> softmax -> P into A_lds cols 512..543
// main   : 17 K-tiles, double-buffered global_load_lds staging, counted vmcnt(4)
// epilog : out = 0.2*acc + T, per-row norm reduce, L1 loss
#define KTILES 17
__global__ __launch_bounds__(512, 2) void k_A2(const float* __restrict__ T,
                                               const u32* __restrict__ Bhs,
                                               const u32* __restrict__ Chs,
                                               float* __restrict__ out,
                                               float* __restrict__ loss_acc) {
    __shared__ __align__(16) _Float16 Ash[64 * 544];      // row stride 544 halves, XOR-swizzled granules
    __shared__ __align__(16) _Float16 Bsh[2][512 * 32];   // [col][32 k] per tile, XOR-swizzled kg
    __shared__ float nrm_inv[64];
    __shared__ float rowss[64];

    const int tid = threadIdx.x;
    const int w = tid >> 6;
    const int lane = tid & 63;
    const int h = lane >> 5;
    const int li = lane & 31;
    const size_t base = (size_t)blockIdx.x * (64 * DIM);
    const char* BhsB = (const char*)Bhs;
    const char* ChsB = (const char*)Chs;

    // --- issue async stages: cacheT -> Bsh[1], B tile0 -> Bsh[0] (overlaps A build)
    {
        int off = w * 1024;
#pragma unroll
        for (int i = 0; i < 4; ++i)
            gload16(ChsB + i * 8192 + off + lane * 16, (char*)&Bsh[1][0] + i * 8192 + off);
#pragma unroll
        for (int i = 0; i < 4; ++i)
            gload16(BhsB + i * 8192 + off + lane * 16, (char*)&Bsh[0][0] + i * 8192 + off);
    }

    // --- load T tile, convert to fp16 swizzled A_lds, compute row norms
    {
        int r = tid >> 3, seg = tid & 7;
        const float4* tp = (const float4*)(T + base + (size_t)r * DIM + seg * 64);
        float ss = 0.f;
#pragma unroll
        for (int i = 0; i < 8; ++i) {
            float4 x0 = tp[2 * i], x1 = tp[2 * i + 1];
            ss += x0.x * x0.x + x0.y * x0.y + x0.z * x0.z + x0.w * x0.w
                + x1.x * x1.x + x1.y * x1.y + x1.z * x1.z + x1.w * x1.w;
            half8 hv;
            hv[0] = (_Float16)x0.x; hv[1] = (_Float16)x0.y; hv[2] = (_Float16)x0.z; hv[3] = (_Float16)x0.w;
            hv[4] = (_Float16)x1.x; hv[5] = (_Float16)x1.y; hv[6] = (_Float16)x1.z; hv[7] = (_Float16)x1.w;
            int gp = (seg << 3) | (i ^ (r & 7));
            *(half8*)&Ash[r * 544 + (gp << 3)] = hv;
        }
        ss += __shfl_xor(ss, 1); ss += __shfl_xor(ss, 2); ss += __shfl_xor(ss, 4);
        if (seg == 0) nrm_inv[r] = 1.0f / fmaxf(sqrtf(ss), 1e-12f);
        if (tid < 64) rowss[tid] = 0.f;
    }

    asm volatile("s_waitcnt vmcnt(0) lgkmcnt(0)" ::: "memory");
    __builtin_amdgcn_s_barrier();
    asm volatile("" ::: "memory");

    // --- phase 1 (waves 0,1): raw scores via MFMA -> softmax -> P into Ash k=512..543
    if (w < 2) {
        floatx16 sacc = (floatx16)0.0f;
        const int m = (w << 5) + li;
        const int mx7 = m & 7;
#pragma unroll 4
        for (int kk2 = 0; kk2 < 32; ++kk2) {
            int g = (kk2 << 1) + h;
            int gp = (g & ~7) | ((g & 7) ^ mx7);
            half8 av = *(const half8*)&Ash[m * 544 + (gp << 3)];
            int gj = (g & ~7) | ((g & 7) ^ (li & 7));
            half8 bv = *(const half8*)&Bsh[1][li * 512 + (gj << 3)];
            sacc = __builtin_amdgcn_mfma_f32_32x32x16_f16(av, bv, sacc, 0, 0, 0);
        }
#pragma unroll
        for (int r = 0; r < 16; ++r) {
            int mr = (w << 5) + (r & 3) + ((r >> 2) << 3) + (h << 2);
            float s = sacc[r] * nrm_inv[mr];
            if (li >= MSLOT) s = -1e30f;
            float mx = s;
            mx = fmaxf(mx, __shfl_xor(mx, 1));
            mx = fmaxf(mx, __shfl_xor(mx, 2));
            mx = fmaxf(mx, __shfl_xor(mx, 4));
            mx = fmaxf(mx, __shfl_xor(mx, 8));
            mx = fmaxf(mx, __shfl_xor(mx, 16));
            float e = expf(s - mx);
            float sum = e;
            sum += __shfl_xor(sum, 1); sum += __shfl_xor(sum, 2);
            sum += __shfl_xor(sum, 4); sum += __shfl_xor(sum, 8); sum += __shfl_xor(sum, 16);
            float pv = e / sum;
            int gp2 = 64 + ((li >> 3) ^ (mr & 3));
            Ash[mr * 544 + (gp2 << 3) + (li & 7)] = (_Float16)pv;
        }
    }
    asm volatile("s_waitcnt lgkmcnt(0)" ::: "memory");
    __builtin_amdgcn_s_barrier();
    asm volatile("" ::: "memory");

    // --- stage B tile1 -> Bsh[1] (cacheT no longer needed)
    {
        int off = w * 1024;
#pragma unroll
        for (int i = 0; i < 4; ++i)
            gload16(BhsB + 32768 + i * 8192 + off + lane * 16, (char*)&Bsh[1][0] + i * 8192 + off);
    }

    // --- main K loop: wave w owns cols [w*64, w*64+64), all 64 rows
    floatx16 acc00 = (floatx16)0.0f, acc01 = (floatx16)0.0f;
    floatx16 acc10 = (floatx16)0.0f, acc11 = (floatx16)0.0f;
    const int cw = w << 6;
    const int c0 = cw + li, c1 = cw + 32 + li;
    const int swz = (c0 >> 1) & 3;           // same for c1 (=c0+32)
    const int arow0 = li * 544, arow1 = (32 + li) * 544;
    const int ax7 = li & 7, ax3 = li & 3;

    for (int t = 0; t < KTILES; ++t) {
        if (t < KTILES - 1) { asm volatile("s_waitcnt vmcnt(4)" ::: "memory"); }
        else                { asm volatile("s_waitcnt vmcnt(0)" ::: "memory"); }
        __builtin_amdgcn_s_barrier();
        asm volatile("" ::: "memory");
        const _Float16* Bt = Bsh[t & 1];
#pragma unroll
        for (int kk = 0; kk < 2; ++kk) {
            int g = (t << 2) + (kk << 1) + h;
            int gp = (g < 64) ? ((g & ~7) | ((g & 7) ^ ax7)) : (64 + ((g & 3) ^ ax3));
            half8 a0 = *(const half8*)&Ash[arow0 + (gp << 3)];
            half8 a1 = *(const half8*)&Ash[arow1 + (gp << 3)];
            int kg = (kk << 1) + h;
            half8 b0 = *(const half8*)&Bt[(c0 << 5) + ((kg ^ swz) << 3)];
            half8 b1 = *(const half8*)&Bt[(c1 << 5) + ((kg ^ swz) << 3)];
            acc00 = __builtin_amdgcn_mfma_f32_32x32x16_f16(a0, b0, acc00, 0, 0, 0);
            acc01 = __builtin_amdgcn_mfma_f32_32x32x16_f16(a0, b1, acc01, 0, 0, 0);
            acc10 = __builtin_amdgcn_mfma_f32_32x32x16_f16(a1, b0, acc10, 0, 0, 0);
            acc11 = __builtin_amdgcn_mfma_f32_32x32x16_f16(a1, b1, acc11, 0, 0, 0);
        }
        asm volatile("" ::: "memory");
        __builtin_amdgcn_s_barrier();
        if (t + 2 < KTILES) {
            int off = w * 1024;
            const char* src = BhsB + (size_t)(t + 2) * 32768;
            char* dstc = (char*)&Bsh[t & 1][0];
#pragma unroll
            for (int i = 0; i < 4; ++i)
                gload16(src + i * 8192 + off + lane * 16, dstc + i * 8192 + off);
        }
    }

    // --- epilogue pass 1: residual + store + row sum-of-squares
    const float* Tg = T + base;
    float* outg = out + base;
#pragma unroll
    for (int r = 0; r < 16; ++r) {
        int lr = (r & 3) + ((r >> 2) << 3) + (h << 2);
        int row0 = lr, row1 = 32 + lr;
        float v00 = ALPHA * acc00[r] + Tg[row0 * DIM + c0];
        float v01 = ALPHA * acc01[r] + Tg[row0 * DIM + c1];
        float v10 = ALPHA * acc10[r] + Tg[row1 * DIM + c0];
        float v11 = ALPHA * acc11[r] + Tg[row1 * DIM + c1];
        outg[row0 * DIM + c0] = v00;
        outg[row0 * DIM + c1] = v01;
        outg[row1 * DIM + c0] = v10;
        outg[row1 * DIM + c1] = v11;
        float s20 = v00 * v00 + v01 * v01;
        float s21 = v10 * v10 + v11 * v11;
        s20 += __shfl_xor(s20, 1); s20 += __shfl_xor(s20, 2); s20 += __shfl_xor(s20, 4);
        s20 += __shfl_xor(s20, 8); s20 += __shfl_xor(s20, 16);
        s21 += __shfl_xor(s21, 1); s21 += __shfl_xor(s21, 2); s21 += __shfl_xor(s21, 4);
        s21 += __shfl_xor(s21, 8); s21 += __shfl_xor(s21, 16);
        if (li == 0) { atomicAdd(&rowss[row0], s20); atomicAdd(&rowss[row1], s21); }
        acc00[r] = v00; acc01[r] = v01; acc10[r] = v10; acc11[r] = v11;
    }
    asm volatile("s_waitcnt lgkmcnt(0)" ::: "memory");
    __builtin_amdgcn_s_barrier();
    asm volatile("" ::: "memory");

    // --- epilogue pass 2: loss
    float lp = 0.f;
#pragma unroll
    for (int r = 0; r < 16; ++r) {
        int lr = (r & 3) + ((r >> 2) << 3) + (h << 2);
        int row0 = lr, row1 = 32 + lr;
        float inv0 = 1.0f / fmaxf(sqrtf(rowss[row0]), 1e-12f);
        float inv1 = 1.0f / fmaxf(sqrtf(rowss[row1]), 1e-12f);
        float t00 = Tg[row0 * DIM + c0];
        float t01 = Tg[row0 * DIM + c1];
        float t10 = Tg[row1 * DIM + c0];
        float t11 = Tg[row1 * DIM + c1];
        lp += fabsf(acc00[r] * inv0 - t00) + fabsf(acc01[r] * inv0 - t01)
            + fabsf(acc10[r] * inv1 - t10) + fabsf(acc11[r] * inv1 - t11);
    }
    lp += __shfl_xor(lp, 32); lp += __shfl_xor(lp, 16); lp += __shfl_xor(lp, 8);
    lp += __shfl_xor(lp, 4);  lp += __shfl_xor(lp, 2);  lp += __shfl_xor(lp, 1);
    if (lane == 0) atomicAdd(loss_acc, lp);
}

// ---------------- image path pass 1: scores, per-row argmax+val, norms, per-slot col max ----------------
__global__ __launch_bounds__(256) void k_B1(const float* __restrict__ I,
                                            const float* __restrict__ C,
                                            float* __restrict__ sia,
                                            int* __restrict__ aw,
                                            float* __restrict__ nr,
                                            u32* __restrict__ cmax) {
    __shared__ __align__(16) float t_flat[TB * DIM];
    __shared__ float sp[TB * MSLOT];
    __shared__ float nrm[TB];
    const int tid = threadIdx.x;
    const size_t base = (size_t)blockIdx.x * (TB * DIM);

    const float4* src = (const float4*)(I + base);
    float4* dst = (float4*)t_flat;
    for (int v = tid; v < TB * DIM / 4; v += 256) dst[v] = src[v];
    __syncthreads();
    {
        int tt = tid >> 4, l = tid & 15;
        float ss = 0.f;
        for (int c = l; c < DIM; c += 16) { float x = t_flat[tt * DIM + c]; ss += x * x; }
        ss += __shfl_xor(ss, 8, 16);
        ss += __shfl_xor(ss, 4, 16);
        ss += __shfl_xor(ss, 2, 16);
        ss += __shfl_xor(ss, 1, 16);
        if (l == 0) nrm[tt] = sqrtf(ss);
    }
    __syncthreads();
    for (int pr = tid; pr < TB * MSLOT; pr += 256) {
        int tt = pr / MSLOT, j = pr - tt * MSLOT;
        const float4* c4 = (const float4*)(C + j * DIM);
        const float4* tp = (const float4*)&t_flat[tt * DIM];
        float acc = 0.f;
        for (int kc = 0; kc < DIM / 4; kc++) {
            float4 cv = c4[kc], q = tp[kc];
            acc += cv.x * q.x + cv.y * q.y + cv.z * q.z + cv.w * q.w;
        }
        sp[pr] = acc / fmaxf(nrm[tt], 1e-12f);
    }
    __syncthreads();
    if (tid < TB) {
        int tok = blockIdx.x * TB + tid;
        nr[tok] = nrm[tid];
        float best = sp[tid * MSLOT];
        int bj = 0;
        for (int j = 1; j < MSLOT; j++) {
            float v = sp[tid * MSLOT + j];
            if (v > best) { best = v; bj = j; }
        }
        aw[tok] = bj;
        sia[tok] = best;
    }
    if (tid < MSLOT) {
        float m = sp[tid];
        for (int tt = 1; tt < TB; tt++) m = fmaxf(m, sp[tt * MSLOT + tid]);
        atomicMax(&cmax[tid], f2sort(m));
    }
}

// ---------------- image path pass 2: scatter EMA accumulation (LDS per-block, column-owned) ----------------
#define B2_BLOCKS 512
#define B2_CHUNK (NTOK / B2_BLOCKS)
__global__ __launch_bounds__(256) void k_B2(const float* __restrict__ I,
                                            const float* __restrict__ sia,
                                            const int* __restrict__ aw,
                                            const float* __restrict__ nr,
                                            const u32* __restrict__ cmax,
                                            float* __restrict__ seg,
                                            float* __restrict__ cnt) {
    __shared__ float segb[MSLOT * DIM];
    __shared__ float cntb[MSLOT];
    __shared__ float cm[MSLOT];
    const int tid = threadIdx.x;
    for (int i = tid; i < MSLOT * DIM; i += 256) segb[i] = 0.f;
    if (tid < MSLOT) { cntb[tid] = 0.f; cm[tid] = sort2f(cmax[tid]); }
    __syncthreads();
    const int i0 = blockIdx.x * B2_CHUNK;
    const float2* ip = (const float2*)I;
    for (int t = 0; t < B2_CHUNK; t++) {
        int i = i0 + t;
        int a = aw[i];
        float scale = expf(sia[i] - cm[a]) / fmaxf(nr[i], 1e-12f);
        float2 v = ip[(size_t)i * (DIM / 2) + tid];
        segb[a * DIM + 2 * tid]     += scale * v.x;
        segb[a * DIM + 2 * tid + 1] += scale * v.y;
        if (tid == 0) cntb[a] += 1.0f;
    }
    __syncthreads();
    for (int idx = tid; idx < MSLOT * DIM; idx += 256) atomicAdd(&seg[idx], segb[idx]);
    if (tid < MSLOT) atomicAdd(&cnt[tid], cntb[tid]);
}

// ---------------- finalize: upd rows + loss scalar ----------------
__global__ __launch_bounds__(256) void k_fin(const float* __restrict__ C,
                                             const float* __restrict__ seg,
                                             const float* __restrict__ cnt,
                                             const float* __restrict__ loss_acc,
                                             float* __restrict__ out) {
    const int b = blockIdx.x, tid = threadIdx.x;
    if (b == MSLOT) {
        if (tid == 0) out[(size_t)NTOK * DIM] = loss_acc[0] * (1.0f / 67108864.0f);
        return;
    }
    __shared__ float wred[4];
    __shared__ float nrm_s;
    const int c0 = 2 * tid;
    float ca0 = C[b * DIM + c0];
    float ca1 = C[b * DIM + c0 + 1];
    bool has = cnt[b] > 0.f;
    float v0 = has ? MOMENTUM * ca0 + (1.0f - MOMENTUM) * seg[b * DIM + c0]     : ca0;
    float v1 = has ? MOMENTUM * ca1 + (1.0f - MOMENTUM) * seg[b * DIM + c0 + 1] : ca1;
    float ss = v0 * v0 + v1 * v1;
    ss += __shfl_xor(ss, 32, 64); ss += __shfl_xor(ss, 16, 64);
    ss += __shfl_xor(ss, 8, 64);  ss += __shfl_xor(ss, 4, 64);
    ss += __shfl_xor(ss, 2, 64);  ss += __shfl_xor(ss, 1, 64);
    if ((tid & 63) == 0) wred[tid >> 6] = ss;
    __syncthreads();
    if (tid == 0) nrm_s = sqrtf(wred[0] + wred[1] + wred[2] + wred[3]);
    __syncthreads();
    float inv = 1.0f / fmaxf(nrm_s, 1e-12f);
    size_t ob = (size_t)NTOK * DIM + 1 + (size_t)b * DIM;
    out[ob + c0]     = v0 * inv;
    out[ob + c0 + 1] = v1 * inv;
}

// ---------------- workspace layout (floats) ----------------
#define OFF_G    0
#define OFF_SEG  12800
#define OFF_CNT  25600
#define OFF_CMAX 25625
#define OFF_LOSS 25650
#define OFF_SIA  25651
#define OFF_A    (25651 + NTOK)
#define OFF_NRM  (25651 + 2 * NTOK)
#define OFF_BHS  418880
#define OFF_CHS  (OFF_BHS + BHS_U32)

extern "C" void kernel_launch(void* const* d_in, const int* in_sizes, int n_in,
                              void* d_out, int out_size, void* d_ws, size_t ws_size,
                              hipStream_t stream) {
    const float* T = (const float*)d_in[0];   // text_token  [N, D] f32
    const float* I = (const float*)d_in[1];   // image_token [N, D] f32
    const float* W = (const float*)d_in[2];   // W [D, 2D] f32
    const float* C = (const float*)d_in[3];   // cache [M, D] f32
    float* out = (float*)d_out;

    float* ws   = (float*)d_ws;
    float* G    = ws + OFF_G;
    float* seg  = ws + OFF_SEG;
    float* cnt  = ws + OFF_CNT;
    u32*   cmax = (u32*)(ws + OFF_CMAX);
    float* loss = ws + OFF_LOSS;
    float* sia  = ws + OFF_SIA;
    int*   aw   = (int*)(ws + OFF_A);
    float* nr   = ws + OFF_NRM;
    u32*   Bhs  = (u32*)(ws + OFF_BHS);
    u32*   Chs  = (u32*)(ws + OFF_CHS);

    // zero seg/cnt/cmax(sortable -inf = 0)/loss in one contiguous memset
    hipMemsetAsync(seg, 0, (size_t)(12800 + 25 + 25 + 1) * sizeof(float), stream);

    hipLaunchKernelGGL(k_G,    dim3(50),        dim3(256), 0, stream, W, C, G);
    hipLaunchKernelGGL(k_pack, dim3(576),       dim3(256), 0, stream, W, C, G, Bhs, Chs);
    hipLaunchKernelGGL(k_A2,   dim3(NTOK / 64), dim3(512), 0, stream, T, Bhs, Chs, out, loss);
    hipLaunchKernelGGL(k_B1,   dim3(NTOK / TB), dim3(256), 0, stream, I, C, sia, aw, nr, cmax);
    hipLaunchKernelGGL(k_B2,   dim3(B2_BLOCKS), dim3(256), 0, stream, I, sia, aw, nr, cmax, seg, cnt);
    hipLaunchKernelGGL(k_fin,  dim3(MSLOT + 1), dim3(256), 0, stream, C, seg, cnt, loss, out);
}